// Round 19
// baseline (131.233 us; speedup 1.0000x reference)
//
#include <hip/hip_runtime.h>

// ---------- types ----------
typedef __bf16 bf16x8 __attribute__((ext_vector_type(8)));
typedef float  f32x4  __attribute__((ext_vector_type(4)));
typedef unsigned int u32x2 __attribute__((ext_vector_type(2)));
typedef unsigned short u16x8 __attribute__((ext_vector_type(8)));
typedef __attribute__((address_space(3))) const unsigned short* lds_cp;

#define T_SEQ 2048
#define C_DIM 1024
#define NH    16
#define HD    64
#define LOG2E 1.4426950408889634f

__device__ __forceinline__ unsigned short f2bf(float f) {
  unsigned u = __builtin_bit_cast(unsigned, f);
  u += 0x7FFFu + ((u >> 16) & 1u);          // round-to-nearest-even
  return (unsigned short)(u >> 16);
}

__device__ __forceinline__ unsigned cvtpk(float lo, float hi) {
  unsigned r;
  asm("v_cvt_pk_bf16_f32 %0, %1, %2" : "=v"(r) : "v"(lo), "v"(hi));
  return r;
}

// HW transpose read. Lane p of each 16-lane group supplies
// addr = group_base + p*8 BYTES; transpose delivers elem j = base_elem + p + j*16.
__device__ __forceinline__ bf16x8 tr_frag(lds_cp addr) {
  u32x2 lo, hi;
  asm volatile("ds_read_b64_tr_b16 %0, %2 offset:0\n\t"
               "ds_read_b64_tr_b16 %1, %2 offset:128"
               : "=&v"(lo), "=&v"(hi) : "v"(addr) : "memory");
  struct { u32x2 a, b; } s{lo, hi};
  return __builtin_bit_cast(bf16x8, s);
}

__device__ __forceinline__ void gload_lds16(const void* g, void* l) {
  __builtin_amdgcn_global_load_lds(
      (const __attribute__((address_space(1))) unsigned int*)g,
      (__attribute__((address_space(3))) unsigned int*)l, 16, 0, 0);
}

// ---------- fused prep: x->bf16, bias concat, 4x weight transpose ----------
__global__ void k_prep(const float* __restrict__ x, unsigned short* __restrict__ xb,
                       const float* __restrict__ bq, const float* __restrict__ bk,
                       const float* __restrict__ bv, float* __restrict__ bqkv,
                       const float* __restrict__ Wq, const float* __restrict__ Wk,
                       const float* __restrict__ Wv, const float* __restrict__ Wp,
                       unsigned short* __restrict__ Wt,   // [3][1024][1024]
                       unsigned short* __restrict__ Wpt) {
  __shared__ float tile[32][33];
  const int bx = blockIdx.x;
  if (bx < 4096) {
    const int i = bx * 256 + threadIdx.x;
    const float4 v = ((const float4*)x)[i];
    ushort4 o;
    o.x = f2bf(v.x); o.y = f2bf(v.y); o.z = f2bf(v.z); o.w = f2bf(v.w);
    ((ushort4*)xb)[i] = o;
  } else if (bx < 4108) {
    const int i = (bx - 4096) * 256 + threadIdx.x;   // 0..3071
    bqkv[i] = (i < 1024) ? bq[i] : (i < 2048 ? bk[i - 1024] : bv[i - 2048]);
  } else {
    const int bi  = bx - 4108;                 // 0..4095
    const int z   = bi >> 10;                  // matrix 0..3
    const int idx = bi & 1023;                 // 32x32 tile id
    const int n0  = (idx & 31) * 32, k0 = (idx >> 5) * 32;
    const float* W = (z == 0) ? Wq : (z == 1) ? Wk : (z == 2) ? Wv : Wp;
    unsigned short* D = (z < 3) ? (Wt + ((size_t)z << 20)) : Wpt;
    const int tx = threadIdx.x & 31, ty = threadIdx.x >> 5;   // 32x8
#pragma unroll
    for (int i = 0; i < 32; i += 8)
      tile[ty + i][tx] = W[(size_t)(k0 + ty + i) * C_DIM + n0 + tx];
    __syncthreads();
#pragma unroll
    for (int i = 0; i < 32; i += 8)
      D[(size_t)(n0 + ty + i) * C_DIM + k0 + tx] = f2bf(tile[tx][ty + i]);
  }
}

// ---------- 128x128 bf16 MFMA GEMM mainloop ----------
template<int KDIM>
__device__ __forceinline__ void gemm_tile_mainloop(
    const unsigned short* __restrict__ A,
    const unsigned short* __restrict__ Bt,
    int m0, int n0,
    unsigned short* As, unsigned short* Bs,
    f32x4 acc[4][4])
{
  const int tid  = threadIdx.x;
  const int lane = tid & 63;
  const int wave = tid >> 6;
  const int wr   = wave >> 1, wc = wave & 1;
  const int srow = lane >> 2;
  const int scol = (lane & 3) << 3;
  const int fr   = lane & 15, g = lane >> 4;

  const f32x4 zero = {0.f, 0.f, 0.f, 0.f};
#pragma unroll
  for (int m = 0; m < 4; ++m)
#pragma unroll
    for (int n = 0; n < 4; ++n) acc[m][n] = zero;

  const int nk = KDIM >> 5;
  for (int kt = 0; kt < nk; ++kt) {
    const int kb = kt << 5;
#pragma unroll
    for (int i = 0; i < 2; ++i) {
      const int c   = wave * 2 + i;
      const int row = c * 16 + srow;
      gload_lds16(A  + (size_t)(m0 + row) * KDIM + kb + scol, As + c * 512);
      gload_lds16(Bt + (size_t)(n0 + row) * KDIM + kb + scol, Bs + c * 512);
    }
    __syncthreads();
    bf16x8 af[4], bfr[4];
    const unsigned short* ap = As + (wr * 64 + fr) * 32 + g * 8;
    const unsigned short* bp = Bs + (wc * 64 + fr) * 32 + g * 8;
#pragma unroll
    for (int m = 0; m < 4; ++m) af[m]  = *(const bf16x8*)(ap + m * 512);
#pragma unroll
    for (int n = 0; n < 4; ++n) bfr[n] = *(const bf16x8*)(bp + n * 512);
#pragma unroll
    for (int m = 0; m < 4; ++m)
#pragma unroll
      for (int n = 0; n < 4; ++n)
        acc[m][n] = __builtin_amdgcn_mfma_f32_16x16x32_bf16(af[m], bfr[n], acc[m][n], 0, 0, 0);
    __syncthreads();
  }
}

// ---------- QKV projection GEMM (XCD-affine M-stripes) ----------
__global__ __launch_bounds__(256) void k_gemm_qkv(
    const unsigned short* __restrict__ Xb,
    const unsigned short* __restrict__ Wt,
    const float* __restrict__ bias,
    unsigned short* __restrict__ Qb,     // [b][h][t][d]  (pre-scaled 0.125*log2e)
    unsigned short* __restrict__ Kb,     // [b][h][t][d]
    unsigned short* __restrict__ Vt)     // [b][h][d][t], rows t%4==3 zeroed
{
  __shared__ __attribute__((aligned(16))) unsigned short As[128 * 32];
  __shared__ __attribute__((aligned(16))) unsigned short Bs[128 * 32];
  f32x4 acc[4][4];
  const int bx  = blockIdx.x;
  const int xcd = bx & 7;
  const int jb  = bx >> 3;                     // 0..95
  const int m0  = (xcd * 4 + (jb & 3)) * 128;
  const int n0  = (jb >> 2) * 128;
  gemm_tile_mainloop<1024>(Xb, Wt, m0, n0, As, Bs, acc);

  const int lane = threadIdx.x & 63, wave = threadIdx.x >> 6;
  const int wr = wave >> 1, wc = wave & 1;
  const int fr = lane & 15, g = lane >> 4;
  const int j = n0 >> 10;
#pragma unroll
  for (int ni = 0; ni < 4; ++ni) {
    const int col = n0 + wc * 64 + ni * 16 + fr;
    const int c = col & 1023, h = c >> 6, d = c & 63;
    const float bb = bias[col];
#pragma unroll
    for (int mi = 0; mi < 4; ++mi)
#pragma unroll
      for (int r = 0; r < 4; ++r) {
        const int row = m0 + wr * 64 + mi * 16 + g * 4 + r;
        const int b = row >> 11, t = row & 2047;
        const int bh = b * NH + h;
        const float v = acc[mi][ni][r] + bb;
        if (j == 0)      Qb[((size_t)bh * T_SEQ + t) * HD + d] = f2bf(v * (0.125f * LOG2E));
        else if (j == 1) Kb[((size_t)bh * T_SEQ + t) * HD + d] = f2bf(v);
        else             Vt[((size_t)bh * HD + d) * T_SEQ + t] =
                           ((t & 3) == 3) ? (unsigned short)0 : f2bf(v);
      }
  }
}

// ---------- flash attention: deferred-PV + issue-early STAGE (T14) ----------
// 2 waves/block, 64 q-rows (32/wave), fixed-scale softmax (log2 domain).
// Column mask in DATA (V rows s%4==3 zeroed; l = P @ bones MFMA). XCD-affine
// bh + balanced qtile permutation. Pipeline: per section t —
//   ds-reads (K(t) frags, tr-read P(t-1), V(t) frags) -> STAGE(t+1) ISSUED
//   EARLY -> fence -> QK(t) MFMAs || deferred PV(t-1) MFMAs -> mask/exp/
//   P(t)-write -> barrier (staging loads had the whole body to land; the
//   barrier's vmcnt drain is no longer exposed).
// V frags ping-pong across two NAMED register sets (no runtime indexing).
__global__ __launch_bounds__(128) void k_attn(
    const unsigned short* __restrict__ Qb,
    const unsigned short* __restrict__ Kb,
    const unsigned short* __restrict__ Vt,
    unsigned short* __restrict__ Yb)
{
  __shared__ __attribute__((aligned(128))) unsigned short Ks[2][64][64];    // 16KB
  __shared__ __attribute__((aligned(128))) unsigned short Vs[2][64][64];    // 16KB
  __shared__ __attribute__((aligned(128))) unsigned short Pc[2][2][64][16]; // 8KB

  const int i    = blockIdx.x;                 // 0..1023
  const int xcd  = i & 7;
  const int jj   = i >> 3;                     // 0..127
  const int bh   = xcd * 4 + (jj & 3);         // XCD-affine bh
  const int qs   = jj >> 2;                    // 0..31
  const int so   = qs >> 3;                    // octant
  const int qtile = (so == 0) ? 31 - qs : (so == 1) ? qs - 8
                  : (so == 2) ? 39 - qs : qs - 16;   // balanced permutation
  const int lane  = threadIdx.x & 63;
  const int wave  = threadIdx.x >> 6;          // 0..1
  const int fr = lane & 15, g = lane >> 4;
  const int q0w = qtile * 64 + wave * 32;      // this wave's 32 q-rows
  const int nt = qtile + 1;                    // s-tiles this block processes
  const size_t hbase = (size_t)bh * T_SEQ * HD;
  const unsigned short* Kh = Kb + hbase;
  const unsigned short* Vh = Vt + (size_t)bh * HD * T_SEQ;

  // staging lane constants: chunk = 8 rows x 64 elems (1KB); lane l -> row l>>3,
  // dest col16 = l&7 (linear), source col16 = (l&7) ^ (row&7)  [rule #21]
  const int srow = lane >> 3;
  const int scol = ((lane & 7) ^ srow) << 3;
  const int frx  = (fr & 7) << 3;              // read-side XOR (elems)

  const unsigned short* qp = Qb + hbase + (size_t)(q0w + fr) * HD + g * 8;
  const bf16x8 qA0 = *(const bf16x8*)(qp);
  const bf16x8 qA1 = *(const bf16x8*)(qp + 32);
  const bf16x8 qB0 = *(const bf16x8*)(qp + 16 * HD);
  const bf16x8 qB1 = *(const bf16x8*)(qp + 16 * HD + 32);

  // bones: B-fragment of the masked ones-vector (elem j <-> s == j mod 4)
  const u16x8 bo = {0x3F80u, 0x3F80u, 0x3F80u, 0u, 0x3F80u, 0x3F80u, 0x3F80u, 0u};
  const bf16x8 bones = __builtin_bit_cast(bf16x8, bo);

  const f32x4 zero = {0.f, 0.f, 0.f, 0.f};
  f32x4 yA[4], yB[4], lAcc, lBcc;
#pragma unroll
  for (int n = 0; n < 4; ++n) { yA[n] = zero; yB[n] = zero; }
  lAcc = zero; lBcc = zero;

  char* pwA = (char*)&Pc[wave][0][0][0] + fr * 32 + g * 8;   // +n*512 per 16-s chunk
  char* pwB = (char*)&Pc[wave][1][0][0] + fr * 32 + g * 8;
  lds_cp trA = (lds_cp)(const unsigned short*)&Pc[wave][0][0][0] + fr * 4 + g * 128;
  lds_cp trB = (lds_cp)(const unsigned short*)&Pc[wave][1][0][0] + fr * 4 + g * 128;

  auto STAGE = [&](int buf, int s0) {
#pragma unroll
    for (int i2 = 0; i2 < 4; ++i2) {
      const int c = wave * 4 + i2;             // chunk 0..7
      gload_lds16(Kh + (size_t)(s0 + c * 8 + srow) * HD + scol, &Ks[buf][c * 8][0]);
      gload_lds16(Vh + (size_t)(c * 8 + srow) * T_SEQ + s0 + scol, &Vs[buf][c * 8][0]);
    }
  };

  // One pipeline section. vfPrev: V(t-1) frags (consumed by deferred PV);
  // vfCur: filled with V(t) frags. dopv = (t > 0).
  auto SECTION = [&](int t, const bf16x8 (&vfPrev)[4][2], bf16x8 (&vfCur)[4][2],
                     bool dopv) {
    const int cur = t & 1;
    const int s0 = t * 64;
    const bool diag = (s0 + 63 > q0w);
    // (1) K fragments from swizzled LDS
    bf16x8 kf[4][2];
#pragma unroll
    for (int n = 0; n < 4; ++n) {
      const unsigned short* kr = &Ks[cur][n * 16 + fr][0];
      kf[n][0] = *(const bf16x8*)(kr + ((g * 8) ^ frx));
      kf[n][1] = *(const bf16x8*)(kr + ((32 + g * 8) ^ frx));
    }
    // (2) tr-read of LAST tile's P (in-order DS; before this tile's P writes)
    bf16x8 paA[2], paB[2];
    if (dopv) {
      paA[0] = tr_frag(trA);  paA[1] = tr_frag(trA + 512);
      paB[0] = tr_frag(trB);  paB[1] = tr_frag(trB + 512);
    }
    // (3) V fragments of THIS tile -> regs (Vs[cur] drained at last barrier)
#pragma unroll
    for (int n = 0; n < 4; ++n) {
      const unsigned short* vr = &Vs[cur][n * 16 + fr][0];
      vfCur[n][0] = *(const bf16x8*)(vr + ((g * 8) ^ frx));
      vfCur[n][1] = *(const bf16x8*)(vr + ((32 + g * 8) ^ frx));
    }
    // (4) STAGE(t+1) ISSUED EARLY: whole body to land before barrier drain
    if (t + 1 < nt) STAGE(cur ^ 1, (t + 1) * 64);
    asm volatile("s_waitcnt lgkmcnt(0)" ::: "memory");
    __builtin_amdgcn_sched_barrier(0);
    // (5) QK^T for both sub-tiles (log2 domain)
    f32x4 sA[4], sB[4];
#pragma unroll
    for (int n = 0; n < 4; ++n) {
      f32x4 a = zero, b = zero;
      a = __builtin_amdgcn_mfma_f32_16x16x32_bf16(qA0, kf[n][0], a, 0, 0, 0);
      a = __builtin_amdgcn_mfma_f32_16x16x32_bf16(qA1, kf[n][1], a, 0, 0, 0);
      b = __builtin_amdgcn_mfma_f32_16x16x32_bf16(qB0, kf[n][0], b, 0, 0, 0);
      b = __builtin_amdgcn_mfma_f32_16x16x32_bf16(qB1, kf[n][1], b, 0, 0, 0);
      sA[n] = a; sB[n] = b;
    }
    // (6) deferred PV(t-1) + l: fills QK's latency window (no dep on sA/sB)
    if (dopv) {
#pragma unroll
      for (int kk = 0; kk < 2; ++kk) {
#pragma unroll
        for (int n = 0; n < 4; ++n) {
          yA[n] = __builtin_amdgcn_mfma_f32_16x16x32_bf16(paA[kk], vfPrev[n][kk], yA[n], 0, 0, 0);
          yB[n] = __builtin_amdgcn_mfma_f32_16x16x32_bf16(paB[kk], vfPrev[n][kk], yB[n], 0, 0, 0);
        }
        lAcc = __builtin_amdgcn_mfma_f32_16x16x32_bf16(paA[kk], bones, lAcc, 0, 0, 0);
        lBcc = __builtin_amdgcn_mfma_f32_16x16x32_bf16(paB[kk], bones, lBcc, 0, 0, 0);
      }
    }
    // (7) causal mask (column mask lives in V/bones)
    if (diag) {
#pragma unroll
      for (int n = 0; n < 4; ++n) {
        const int sc = s0 + n * 16 + fr;
#pragma unroll
        for (int r = 0; r < 4; ++r) {
          const int tA = q0w + g * 4 + r;
          sA[n][r] = (sc <= tA) ? sA[n][r] : -1e30f;
          sB[n][r] = (sc <= tA + 16) ? sB[n][r] : -1e30f;
        }
      }
    }
    // (8) p = exp2(S), cvt_pk, ds_write col-major (tr-reads already complete)
#pragma unroll
    for (int n = 0; n < 4; ++n) {
      u32x2 wa = {cvtpk(exp2f(sA[n][0]), exp2f(sA[n][1])),
                  cvtpk(exp2f(sA[n][2]), exp2f(sA[n][3]))};
      u32x2 wb = {cvtpk(exp2f(sB[n][0]), exp2f(sB[n][1])),
                  cvtpk(exp2f(sB[n][2]), exp2f(sB[n][3]))};
      *(u32x2*)(pwA + n * 512) = wa;
      *(u32x2*)(pwB + n * 512) = wb;
    }
  };

  auto FINALPV = [&](const bf16x8 (&vf)[4][2]) {
    bf16x8 paA[2], paB[2];
    paA[0] = tr_frag(trA);  paA[1] = tr_frag(trA + 512);
    paB[0] = tr_frag(trB);  paB[1] = tr_frag(trB + 512);
    asm volatile("s_waitcnt lgkmcnt(0)" ::: "memory");
    __builtin_amdgcn_sched_barrier(0);
#pragma unroll
    for (int kk = 0; kk < 2; ++kk) {
#pragma unroll
      for (int n = 0; n < 4; ++n) {
        yA[n] = __builtin_amdgcn_mfma_f32_16x16x32_bf16(paA[kk], vf[n][kk], yA[n], 0, 0, 0);
        yB[n] = __builtin_amdgcn_mfma_f32_16x16x32_bf16(paB[kk], vf[n][kk], yB[n], 0, 0, 0);
      }
      lAcc = __builtin_amdgcn_mfma_f32_16x16x32_bf16(paA[kk], bones, lAcc, 0, 0, 0);
      lBcc = __builtin_amdgcn_mfma_f32_16x16x32_bf16(paB[kk], bones, lBcc, 0, 0, 0);
    }
  };

  // ---- pipeline: V-frag register ping-pong across named sets ----
  bf16x8 va[4][2], vb[4][2];                   // va holds V(t) for even t
  STAGE(0, 0);
  __syncthreads();
  SECTION(0, vb, va, false);
  __syncthreads();
  int t = 1;
  while (t < nt) {
    SECTION(t, va, vb, true);                  // odd t fills vb
    __syncthreads();
    if (++t >= nt) break;
    SECTION(t, vb, va, true);                  // even t fills va
    __syncthreads();
    ++t;
  }
  if ((nt - 1) & 1) FINALPV(vb); else FINALPV(va);

  // ---- epilogue: l came out of MFMA already row-broadcast; just divide ----
  const int b = bh >> 4, h = bh & 15;
#pragma unroll
  for (int r = 0; r < 4; ++r) {
    const float invA = 1.0f / lAcc[r], invB = 1.0f / lBcc[r];
    const int tA = q0w + g * 4 + r;
#pragma unroll
    for (int n = 0; n < 4; ++n) {
      Yb[((size_t)(b * T_SEQ + tA)) * C_DIM + h * HD + n * 16 + fr] = f2bf(yA[n][r] * invA);
      Yb[((size_t)(b * T_SEQ + tA + 16)) * C_DIM + h * HD + n * 16 + fr] = f2bf(yB[n][r] * invB);
    }
  }
}

// ---------- output projection (XCD-affine M-stripes) ----------
__global__ __launch_bounds__(256) void k_gemm_out(
    const unsigned short* __restrict__ Yb,
    const unsigned short* __restrict__ Wpt,
    const float* __restrict__ bp,
    float* __restrict__ out)
{
  __shared__ __attribute__((aligned(16))) unsigned short As[128 * 32];
  __shared__ __attribute__((aligned(16))) unsigned short Bs[128 * 32];
  f32x4 acc[4][4];
  const int bx  = blockIdx.x;
  const int xcd = bx & 7;
  const int jb  = bx >> 3;                     // 0..31
  const int m0  = (xcd * 4 + (jb & 3)) * 128;
  const int n0  = (jb >> 2) * 128;
  gemm_tile_mainloop<1024>(Yb, Wpt, m0, n0, As, Bs, acc);

  const int lane = threadIdx.x & 63, wave = threadIdx.x >> 6;
  const int wr = wave >> 1, wc = wave & 1;
  const int fr = lane & 15, g = lane >> 4;
#pragma unroll
  for (int ni = 0; ni < 4; ++ni) {
    const int col = n0 + wc * 64 + ni * 16 + fr;
    const float bb = bp[col];
#pragma unroll
    for (int mi = 0; mi < 4; ++mi)
#pragma unroll
      for (int r = 0; r < 4; ++r) {
        const int row = m0 + wr * 64 + mi * 16 + g * 4 + r;
        out[(size_t)row * C_DIM + col] = acc[mi][ni][r] + bb;
      }
  }
}

// ---------- launch ----------
extern "C" void kernel_launch(void* const* d_in, const int* in_sizes, int n_in,
                              void* d_out, int out_size, void* d_ws, size_t ws_size,
                              hipStream_t stream) {
  const float* x  = (const float*)d_in[0];
  const float* Wq = (const float*)d_in[1];
  const float* bq = (const float*)d_in[2];
  const float* Wk = (const float*)d_in[3];
  const float* bk = (const float*)d_in[4];
  const float* Wv = (const float*)d_in[5];
  const float* bv = (const float*)d_in[6];
  const float* Wp = (const float*)d_in[7];
  const float* bp = (const float*)d_in[8];
  float* out = (float*)d_out;

  char* ws = (char*)d_ws;
  unsigned short* Xb   = (unsigned short*)(ws);                             // 8 MB
  unsigned short* Wt   = (unsigned short*)(ws + (8u  << 20));               // 6 MB
  unsigned short* Wpt  = (unsigned short*)(ws + (14u << 20));               // 2 MB
  float*          bqkv = (float*)         (ws + (16u << 20));               // 12 KB
  unsigned short* Qb   = (unsigned short*)(ws + (16u << 20) + (64u << 10)); // 8 MB
  unsigned short* Kb   = (unsigned short*)(ws + (24u << 20) + (64u << 10)); // 8 MB
  unsigned short* Vt   = (unsigned short*)(ws + (32u << 20) + (64u << 10)); // 8 MB
  unsigned short* Yb   = (unsigned short*)(ws + (40u << 20) + (64u << 10)); // 8 MB

  k_prep<<<8204, 256, 0, stream>>>(x, Xb, bq, bk, bv, bqkv, Wq, Wk, Wv, Wp, Wt, Wpt);
  k_gemm_qkv<<<dim3(768), 256, 0, stream>>>(Xb, Wt, bqkv, Qb, Kb, Vt);
  k_attn<<<dim3(1024), 128, 0, stream>>>(Qb, Kb, Vt, Yb);
  k_gemm_out<<<dim3(256), 256, 0, stream>>>(Yb, Wpt, bp, out);
}

// Round 20
// 119.895 us; speedup vs baseline: 1.0946x; 1.0946x over previous
//
#include <hip/hip_runtime.h>

// ---------- types ----------
typedef __bf16 bf16x8 __attribute__((ext_vector_type(8)));
typedef float  f32x4  __attribute__((ext_vector_type(4)));
typedef unsigned int u32x2 __attribute__((ext_vector_type(2)));
typedef unsigned short u16x8 __attribute__((ext_vector_type(8)));
typedef __attribute__((address_space(3))) const unsigned short* lds_cp;

#define T_SEQ 2048
#define C_DIM 1024
#define NH    16
#define HD    64
#define LOG2E 1.4426950408889634f

__device__ __forceinline__ unsigned short f2bf(float f) {
  unsigned u = __builtin_bit_cast(unsigned, f);
  u += 0x7FFFu + ((u >> 16) & 1u);          // round-to-nearest-even
  return (unsigned short)(u >> 16);
}

__device__ __forceinline__ unsigned cvtpk(float lo, float hi) {
  unsigned r;
  asm("v_cvt_pk_bf16_f32 %0, %1, %2" : "=v"(r) : "v"(lo), "v"(hi));
  return r;
}

// HW transpose read. Lane p of each 16-lane group supplies
// addr = group_base + p*8 BYTES; transpose delivers elem j = base_elem + p + j*16.
__device__ __forceinline__ bf16x8 tr_frag(lds_cp addr) {
  u32x2 lo, hi;
  asm volatile("ds_read_b64_tr_b16 %0, %2 offset:0\n\t"
               "ds_read_b64_tr_b16 %1, %2 offset:128"
               : "=&v"(lo), "=&v"(hi) : "v"(addr) : "memory");
  struct { u32x2 a, b; } s{lo, hi};
  return __builtin_bit_cast(bf16x8, s);
}

__device__ __forceinline__ void gload_lds16(const void* g, void* l) {
  __builtin_amdgcn_global_load_lds(
      (const __attribute__((address_space(1))) unsigned int*)g,
      (__attribute__((address_space(3))) unsigned int*)l, 16, 0, 0);
}

// ---------- fused prep: x->bf16, bias concat, 4x weight transpose ----------
__global__ void k_prep(const float* __restrict__ x, unsigned short* __restrict__ xb,
                       const float* __restrict__ bq, const float* __restrict__ bk,
                       const float* __restrict__ bv, float* __restrict__ bqkv,
                       const float* __restrict__ Wq, const float* __restrict__ Wk,
                       const float* __restrict__ Wv, const float* __restrict__ Wp,
                       unsigned short* __restrict__ Wt,   // [3][1024][1024]
                       unsigned short* __restrict__ Wpt) {
  __shared__ float tile[32][33];
  const int bx = blockIdx.x;
  if (bx < 4096) {
    const int i = bx * 256 + threadIdx.x;
    const float4 v = ((const float4*)x)[i];
    ushort4 o;
    o.x = f2bf(v.x); o.y = f2bf(v.y); o.z = f2bf(v.z); o.w = f2bf(v.w);
    ((ushort4*)xb)[i] = o;
  } else if (bx < 4108) {
    const int i = (bx - 4096) * 256 + threadIdx.x;   // 0..3071
    bqkv[i] = (i < 1024) ? bq[i] : (i < 2048 ? bk[i - 1024] : bv[i - 2048]);
  } else {
    const int bi  = bx - 4108;                 // 0..4095
    const int z   = bi >> 10;                  // matrix 0..3
    const int idx = bi & 1023;                 // 32x32 tile id
    const int n0  = (idx & 31) * 32, k0 = (idx >> 5) * 32;
    const float* W = (z == 0) ? Wq : (z == 1) ? Wk : (z == 2) ? Wv : Wp;
    unsigned short* D = (z < 3) ? (Wt + ((size_t)z << 20)) : Wpt;
    const int tx = threadIdx.x & 31, ty = threadIdx.x >> 5;   // 32x8
#pragma unroll
    for (int i = 0; i < 32; i += 8)
      tile[ty + i][tx] = W[(size_t)(k0 + ty + i) * C_DIM + n0 + tx];
    __syncthreads();
#pragma unroll
    for (int i = 0; i < 32; i += 8)
      D[(size_t)(n0 + ty + i) * C_DIM + k0 + tx] = f2bf(tile[tx][ty + i]);
  }
}

// ---------- 128x128 bf16 MFMA GEMM mainloop ----------
template<int KDIM>
__device__ __forceinline__ void gemm_tile_mainloop(
    const unsigned short* __restrict__ A,
    const unsigned short* __restrict__ Bt,
    int m0, int n0,
    unsigned short* As, unsigned short* Bs,
    f32x4 acc[4][4])
{
  const int tid  = threadIdx.x;
  const int lane = tid & 63;
  const int wave = tid >> 6;
  const int wr   = wave >> 1, wc = wave & 1;
  const int srow = lane >> 2;
  const int scol = (lane & 3) << 3;
  const int fr   = lane & 15, g = lane >> 4;

  const f32x4 zero = {0.f, 0.f, 0.f, 0.f};
#pragma unroll
  for (int m = 0; m < 4; ++m)
#pragma unroll
    for (int n = 0; n < 4; ++n) acc[m][n] = zero;

  const int nk = KDIM >> 5;
  for (int kt = 0; kt < nk; ++kt) {
    const int kb = kt << 5;
#pragma unroll
    for (int i = 0; i < 2; ++i) {
      const int c   = wave * 2 + i;
      const int row = c * 16 + srow;
      gload_lds16(A  + (size_t)(m0 + row) * KDIM + kb + scol, As + c * 512);
      gload_lds16(Bt + (size_t)(n0 + row) * KDIM + kb + scol, Bs + c * 512);
    }
    __syncthreads();
    bf16x8 af[4], bfr[4];
    const unsigned short* ap = As + (wr * 64 + fr) * 32 + g * 8;
    const unsigned short* bp = Bs + (wc * 64 + fr) * 32 + g * 8;
#pragma unroll
    for (int m = 0; m < 4; ++m) af[m]  = *(const bf16x8*)(ap + m * 512);
#pragma unroll
    for (int n = 0; n < 4; ++n) bfr[n] = *(const bf16x8*)(bp + n * 512);
#pragma unroll
    for (int m = 0; m < 4; ++m)
#pragma unroll
      for (int n = 0; n < 4; ++n)
        acc[m][n] = __builtin_amdgcn_mfma_f32_16x16x32_bf16(af[m], bfr[n], acc[m][n], 0, 0, 0);
    __syncthreads();
  }
}

// ---------- QKV projection GEMM (XCD-affine M-stripes) ----------
__global__ __launch_bounds__(256) void k_gemm_qkv(
    const unsigned short* __restrict__ Xb,
    const unsigned short* __restrict__ Wt,
    const float* __restrict__ bias,
    unsigned short* __restrict__ Qb,     // [b][h][t][d]  (pre-scaled 0.125*log2e)
    unsigned short* __restrict__ Kb,     // [b][h][t][d]
    unsigned short* __restrict__ Vt)     // [b][h][d][t], rows t%4==3 zeroed
{
  __shared__ __attribute__((aligned(16))) unsigned short As[128 * 32];
  __shared__ __attribute__((aligned(16))) unsigned short Bs[128 * 32];
  f32x4 acc[4][4];
  const int bx  = blockIdx.x;
  const int xcd = bx & 7;
  const int jb  = bx >> 3;                     // 0..95
  const int m0  = (xcd * 4 + (jb & 3)) * 128;
  const int n0  = (jb >> 2) * 128;
  gemm_tile_mainloop<1024>(Xb, Wt, m0, n0, As, Bs, acc);

  const int lane = threadIdx.x & 63, wave = threadIdx.x >> 6;
  const int wr = wave >> 1, wc = wave & 1;
  const int fr = lane & 15, g = lane >> 4;
  const int j = n0 >> 10;
#pragma unroll
  for (int ni = 0; ni < 4; ++ni) {
    const int col = n0 + wc * 64 + ni * 16 + fr;
    const int c = col & 1023, h = c >> 6, d = c & 63;
    const float bb = bias[col];
#pragma unroll
    for (int mi = 0; mi < 4; ++mi)
#pragma unroll
      for (int r = 0; r < 4; ++r) {
        const int row = m0 + wr * 64 + mi * 16 + g * 4 + r;
        const int b = row >> 11, t = row & 2047;
        const int bh = b * NH + h;
        const float v = acc[mi][ni][r] + bb;
        if (j == 0)      Qb[((size_t)bh * T_SEQ + t) * HD + d] = f2bf(v * (0.125f * LOG2E));
        else if (j == 1) Kb[((size_t)bh * T_SEQ + t) * HD + d] = f2bf(v);
        else             Vt[((size_t)bh * HD + d) * T_SEQ + t] =
                           ((t & 3) == 3) ? (unsigned short)0 : f2bf(v);
      }
  }
}

// ---------- flash attention: deferred-PV (R18) + early-STAGE hoist only ----------
// 2 waves/block, 64 q-rows (32/wave), fixed-scale softmax (log2 domain).
// Column mask in DATA (V rows s%4==3 zeroed; l = P @ bones MFMA). XCD-affine
// bh + balanced qtile permutation. R18 pipeline (PV(t-1) retires inside
// QK(t)'s latency window) with ONE change: STAGE(t+1) is issued at the TOP
// of the body (address-only; prior readers of Ks/Vs[cur^1] completed before
// the previous barrier), so the 8 staging loads land under ~1200cy of
// compute instead of being drained cold at the barrier. No extra VGPR.
__global__ __launch_bounds__(128) void k_attn(
    const unsigned short* __restrict__ Qb,
    const unsigned short* __restrict__ Kb,
    const unsigned short* __restrict__ Vt,
    unsigned short* __restrict__ Yb)
{
  __shared__ __attribute__((aligned(128))) unsigned short Ks[2][64][64];    // 16KB
  __shared__ __attribute__((aligned(128))) unsigned short Vs[2][64][64];    // 16KB
  __shared__ __attribute__((aligned(128))) unsigned short Pc[2][2][64][16]; // 8KB

  const int i    = blockIdx.x;                 // 0..1023
  const int xcd  = i & 7;
  const int jj   = i >> 3;                     // 0..127
  const int bh   = xcd * 4 + (jj & 3);         // XCD-affine bh
  const int qs   = jj >> 2;                    // 0..31
  const int so   = qs >> 3;                    // octant
  const int qtile = (so == 0) ? 31 - qs : (so == 1) ? qs - 8
                  : (so == 2) ? 39 - qs : qs - 16;   // balanced permutation
  const int lane  = threadIdx.x & 63;
  const int wave  = threadIdx.x >> 6;          // 0..1
  const int fr = lane & 15, g = lane >> 4;
  const int q0w = qtile * 64 + wave * 32;      // this wave's 32 q-rows
  const int nt = qtile + 1;                    // s-tiles this block processes
  const size_t hbase = (size_t)bh * T_SEQ * HD;
  const unsigned short* Kh = Kb + hbase;
  const unsigned short* Vh = Vt + (size_t)bh * HD * T_SEQ;

  // staging lane constants: chunk = 8 rows x 64 elems (1KB); lane l -> row l>>3,
  // dest col16 = l&7 (linear), source col16 = (l&7) ^ (row&7)  [rule #21]
  const int srow = lane >> 3;
  const int scol = ((lane & 7) ^ srow) << 3;
  const int frx  = (fr & 7) << 3;              // read-side XOR (elems)

  const unsigned short* qp = Qb + hbase + (size_t)(q0w + fr) * HD + g * 8;
  const bf16x8 qA0 = *(const bf16x8*)(qp);
  const bf16x8 qA1 = *(const bf16x8*)(qp + 32);
  const bf16x8 qB0 = *(const bf16x8*)(qp + 16 * HD);
  const bf16x8 qB1 = *(const bf16x8*)(qp + 16 * HD + 32);

  // bones: B-fragment of the masked ones-vector (elem j <-> s == j mod 4)
  const u16x8 bo = {0x3F80u, 0x3F80u, 0x3F80u, 0u, 0x3F80u, 0x3F80u, 0x3F80u, 0u};
  const bf16x8 bones = __builtin_bit_cast(bf16x8, bo);

  const f32x4 zero = {0.f, 0.f, 0.f, 0.f};
  f32x4 yA[4], yB[4], lAcc, lBcc;
#pragma unroll
  for (int n = 0; n < 4; ++n) { yA[n] = zero; yB[n] = zero; }
  lAcc = zero; lBcc = zero;
  bf16x8 vfOld[4][2];                          // V frags of tile t (reg-carried)

  char* pwA = (char*)&Pc[wave][0][0][0] + fr * 32 + g * 8;   // +n*512 per 16-s chunk
  char* pwB = (char*)&Pc[wave][1][0][0] + fr * 32 + g * 8;
  lds_cp trA = (lds_cp)(const unsigned short*)&Pc[wave][0][0][0] + fr * 4 + g * 128;
  lds_cp trB = (lds_cp)(const unsigned short*)&Pc[wave][1][0][0] + fr * 4 + g * 128;

  auto STAGE = [&](int buf, int s0) {
#pragma unroll
    for (int i2 = 0; i2 < 4; ++i2) {
      const int c = wave * 4 + i2;             // chunk 0..7
      gload_lds16(Kh + (size_t)(s0 + c * 8 + srow) * HD + scol, &Ks[buf][c * 8][0]);
      gload_lds16(Vh + (size_t)(c * 8 + srow) * T_SEQ + s0 + scol, &Vs[buf][c * 8][0]);
    }
  };

  STAGE(0, 0);
  __syncthreads();
  for (int t = 0; t < nt; ++t) {
    const int cur = t & 1;
    const int s0 = t * 64;
    const bool diag = (s0 + 63 > q0w);
    // (1) K fragments from swizzled LDS
    bf16x8 kf[4][2];
#pragma unroll
    for (int n = 0; n < 4; ++n) {
      const unsigned short* kr = &Ks[cur][n * 16 + fr][0];
      kf[n][0] = *(const bf16x8*)(kr + ((g * 8) ^ frx));
      kf[n][1] = *(const bf16x8*)(kr + ((32 + g * 8) ^ frx));
    }
    // (2) tr-read of LAST tile's P (in-order DS; before this tile's P writes)
    bf16x8 paA[2], paB[2];
    if (t > 0) {
      paA[0] = tr_frag(trA);  paA[1] = tr_frag(trA + 512);
      paB[0] = tr_frag(trB);  paB[1] = tr_frag(trB + 512);
    }
    // (2.5) EARLY STAGE(t+1): loads land under the whole body's compute.
    // Safe: all readers of Ks/Vs[cur^1] finished before the previous barrier.
    if (t + 1 < nt) STAGE(cur ^ 1, (t + 1) * 64);
    asm volatile("s_waitcnt lgkmcnt(0)" ::: "memory");
    __builtin_amdgcn_sched_barrier(0);
    // (3) QK^T for both sub-tiles (log2 domain)
    f32x4 sA[4], sB[4];
#pragma unroll
    for (int n = 0; n < 4; ++n) {
      f32x4 a = zero, b = zero;
      a = __builtin_amdgcn_mfma_f32_16x16x32_bf16(qA0, kf[n][0], a, 0, 0, 0);
      a = __builtin_amdgcn_mfma_f32_16x16x32_bf16(qA1, kf[n][1], a, 0, 0, 0);
      b = __builtin_amdgcn_mfma_f32_16x16x32_bf16(qB0, kf[n][0], b, 0, 0, 0);
      b = __builtin_amdgcn_mfma_f32_16x16x32_bf16(qB1, kf[n][1], b, 0, 0, 0);
      sA[n] = a; sB[n] = b;
    }
    // (4) deferred PV(t-1) + l: fills QK's latency window (no dep on sA/sB)
    if (t > 0) {
#pragma unroll
      for (int kk = 0; kk < 2; ++kk) {
#pragma unroll
        for (int n = 0; n < 4; ++n) {
          yA[n] = __builtin_amdgcn_mfma_f32_16x16x32_bf16(paA[kk], vfOld[n][kk], yA[n], 0, 0, 0);
          yB[n] = __builtin_amdgcn_mfma_f32_16x16x32_bf16(paB[kk], vfOld[n][kk], yB[n], 0, 0, 0);
        }
        lAcc = __builtin_amdgcn_mfma_f32_16x16x32_bf16(paA[kk], bones, lAcc, 0, 0, 0);
        lBcc = __builtin_amdgcn_mfma_f32_16x16x32_bf16(paB[kk], bones, lBcc, 0, 0, 0);
      }
    }
    // (5) causal mask (column mask lives in V/bones)
    if (diag) {
#pragma unroll
      for (int n = 0; n < 4; ++n) {
        const int sc = s0 + n * 16 + fr;
#pragma unroll
        for (int r = 0; r < 4; ++r) {
          const int tA = q0w + g * 4 + r;
          sA[n][r] = (sc <= tA) ? sA[n][r] : -1e30f;
          sB[n][r] = (sc <= tA + 16) ? sB[n][r] : -1e30f;
        }
      }
    }
    // (6) p = exp2(S), cvt_pk, ds_write col-major (tr-reads already complete)
#pragma unroll
    for (int n = 0; n < 4; ++n) {
      u32x2 wa = {cvtpk(exp2f(sA[n][0]), exp2f(sA[n][1])),
                  cvtpk(exp2f(sA[n][2]), exp2f(sA[n][3]))};
      u32x2 wb = {cvtpk(exp2f(sB[n][0]), exp2f(sB[n][1])),
                  cvtpk(exp2f(sB[n][2]), exp2f(sB[n][3]))};
      *(u32x2*)(pwA + n * 512) = wa;
      *(u32x2*)(pwB + n * 512) = wb;
    }
    // (7) V frags of THIS tile -> regs (Vs[cur] not touched by early STAGE)
#pragma unroll
    for (int n = 0; n < 4; ++n) {
      const unsigned short* vr = &Vs[cur][n * 16 + fr][0];
      vfOld[n][0] = *(const bf16x8*)(vr + ((g * 8) ^ frx));
      vfOld[n][1] = *(const bf16x8*)(vr + ((32 + g * 8) ^ frx));
    }
    __syncthreads();
  }
  // final PV for tile nt-1 (P still intact; vfOld holds V(nt-1))
  {
    bf16x8 paA[2], paB[2];
    paA[0] = tr_frag(trA);  paA[1] = tr_frag(trA + 512);
    paB[0] = tr_frag(trB);  paB[1] = tr_frag(trB + 512);
    asm volatile("s_waitcnt lgkmcnt(0)" ::: "memory");
    __builtin_amdgcn_sched_barrier(0);
#pragma unroll
    for (int kk = 0; kk < 2; ++kk) {
#pragma unroll
      for (int n = 0; n < 4; ++n) {
        yA[n] = __builtin_amdgcn_mfma_f32_16x16x32_bf16(paA[kk], vfOld[n][kk], yA[n], 0, 0, 0);
        yB[n] = __builtin_amdgcn_mfma_f32_16x16x32_bf16(paB[kk], vfOld[n][kk], yB[n], 0, 0, 0);
      }
      lAcc = __builtin_amdgcn_mfma_f32_16x16x32_bf16(paA[kk], bones, lAcc, 0, 0, 0);
      lBcc = __builtin_amdgcn_mfma_f32_16x16x32_bf16(paB[kk], bones, lBcc, 0, 0, 0);
    }
  }

  // ---- epilogue: l came out of MFMA already row-broadcast; just divide ----
  const int b = bh >> 4, h = bh & 15;
#pragma unroll
  for (int r = 0; r < 4; ++r) {
    const float invA = 1.0f / lAcc[r], invB = 1.0f / lBcc[r];
    const int tA = q0w + g * 4 + r;
#pragma unroll
    for (int n = 0; n < 4; ++n) {
      Yb[((size_t)(b * T_SEQ + tA)) * C_DIM + h * HD + n * 16 + fr] = f2bf(yA[n][r] * invA);
      Yb[((size_t)(b * T_SEQ + tA + 16)) * C_DIM + h * HD + n * 16 + fr] = f2bf(yB[n][r] * invB);
    }
  }
}

// ---------- output projection (XCD-affine M-stripes) ----------
__global__ __launch_bounds__(256) void k_gemm_out(
    const unsigned short* __restrict__ Yb,
    const unsigned short* __restrict__ Wpt,
    const float* __restrict__ bp,
    float* __restrict__ out)
{
  __shared__ __attribute__((aligned(16))) unsigned short As[128 * 32];
  __shared__ __attribute__((aligned(16))) unsigned short Bs[128 * 32];
  f32x4 acc[4][4];
  const int bx  = blockIdx.x;
  const int xcd = bx & 7;
  const int jb  = bx >> 3;                     // 0..31
  const int m0  = (xcd * 4 + (jb & 3)) * 128;
  const int n0  = (jb >> 2) * 128;
  gemm_tile_mainloop<1024>(Yb, Wpt, m0, n0, As, Bs, acc);

  const int lane = threadIdx.x & 63, wave = threadIdx.x >> 6;
  const int wr = wave >> 1, wc = wave & 1;
  const int fr = lane & 15, g = lane >> 4;
#pragma unroll
  for (int ni = 0; ni < 4; ++ni) {
    const int col = n0 + wc * 64 + ni * 16 + fr;
    const float bb = bp[col];
#pragma unroll
    for (int mi = 0; mi < 4; ++mi)
#pragma unroll
      for (int r = 0; r < 4; ++r) {
        const int row = m0 + wr * 64 + mi * 16 + g * 4 + r;
        out[(size_t)row * C_DIM + col] = acc[mi][ni][r] + bb;
      }
  }
}

// ---------- launch ----------
extern "C" void kernel_launch(void* const* d_in, const int* in_sizes, int n_in,
                              void* d_out, int out_size, void* d_ws, size_t ws_size,
                              hipStream_t stream) {
  const float* x  = (const float*)d_in[0];
  const float* Wq = (const float*)d_in[1];
  const float* bq = (const float*)d_in[2];
  const float* Wk = (const float*)d_in[3];
  const float* bk = (const float*)d_in[4];
  const float* Wv = (const float*)d_in[5];
  const float* bv = (const float*)d_in[6];
  const float* Wp = (const float*)d_in[7];
  const float* bp = (const float*)d_in[8];
  float* out = (float*)d_out;

  char* ws = (char*)d_ws;
  unsigned short* Xb   = (unsigned short*)(ws);                             // 8 MB
  unsigned short* Wt   = (unsigned short*)(ws + (8u  << 20));               // 6 MB
  unsigned short* Wpt  = (unsigned short*)(ws + (14u << 20));               // 2 MB
  float*          bqkv = (float*)         (ws + (16u << 20));               // 12 KB
  unsigned short* Qb   = (unsigned short*)(ws + (16u << 20) + (64u << 10)); // 8 MB
  unsigned short* Kb   = (unsigned short*)(ws + (24u << 20) + (64u << 10)); // 8 MB
  unsigned short* Vt   = (unsigned short*)(ws + (32u << 20) + (64u << 10)); // 8 MB
  unsigned short* Yb   = (unsigned short*)(ws + (40u << 20) + (64u << 10)); // 8 MB

  k_prep<<<8204, 256, 0, stream>>>(x, Xb, bq, bk, bv, bqkv, Wq, Wk, Wv, Wp, Wt, Wpt);
  k_gemm_qkv<<<dim3(768), 256, 0, stream>>>(Xb, Wt, bqkv, Qb, Kb, Vt);
  k_attn<<<dim3(1024), 128, 0, stream>>>(Qb, Kb, Vt, Yb);
  k_gemm_out<<<dim3(256), 256, 0, stream>>>(Yb, Wpt, bp, out);
}